// Round 1
// 136.529 us; speedup vs baseline: 1.0385x; 1.0385x over previous
//
#include <hip/hip_runtime.h>

#define NB 8      // NUM_BLOCK
#define NT 500    // NUM_FRAME
#define NF 257    // NUM_BIN
#define NC 8      // NUM_CH
#define NNUL 4    // NUM_NULL
#define LOWF 5
#define HIGHF 70
#define S_CHUNK 8
#define WARM 4
#define N_CHUNK 63   // ceil(NT / S_CHUNK)
#define AL 0.35f

__device__ __forceinline__ float dot8(const float4& a0, const float4& a1,
                                      const float4& b0, const float4& b1) {
    return a0.x*b0.x + a0.y*b0.y + a0.z*b0.z + a0.w*b0.w
         + a1.x*b1.x + a1.y*b1.y + a1.z*b1.z + a1.w*b1.w;
}

// Fused single-pass kernel: EMA over an 8-frame chunk (+4 warm-up) AND the
// per-(b,t) ratio, fused by making each block cover ALL 257 bins:
// 1024 threads, f = tid>>2 in [0,256), n = tid&3, f=256 on the 4 "extra"
// threads (tid<4). The f-in-[5,70) reduction is then block-local: waves 0..4
// shfl-reduce -> 25 LDS partials -> one __syncthreads per output frame ->
// every thread reads the partials (broadcast), forms ratio, writes FINAL
// sqrt(dcf_pre*ratio). Eliminates kernel2 (33MB rmw of out), ws memset, and
// global atomics. s_part is double-buffered by t-parity so a single barrier
// per frame is race-free.
// Inner per-frame body is the verified R8 body unchanged (60 VGPR there).
// launch_bounds(1024,4): VGPR cap 128 (cap 64 spills this body).
// Grid: (b, chunk) = 504 blocks x 1024 thr (~2 blocks/CU at <=64 VGPR).
__global__ __launch_bounds__(1024, 4) void dcf_fused_kernel(
    const float* __restrict__ x,           // (NB,NT,2,NF,NC) fp32
    const int* __restrict__ beam_id,       // (NB,)
    const float* __restrict__ targ_w,      // (8,2,NF,NC) fp32
    const float* __restrict__ null_w,      // (8,NNUL,2,NF,NC) fp32
    float* __restrict__ out)               // fp32: dcf (NB,NT,NF,NNUL) then targ (NB,NT,2,NF)
{
    const int tid = threadIdx.x;
    const int bid = blockIdx.x;
    const int b  = bid & 7;
    const int k  = bid >> 3;
    const int t0 = k * S_CHUNK;
    const int te = min(NT, t0 + S_CHUNK);
    int ts = t0 - WARM; if (ts < 0) ts = 0;

    const int f = tid >> 2;                // 0..255
    const int n = tid & 3;
    const int wid = tid >> 6;
    const int lane = tid & 63;
    const bool extra = (tid < 4);          // quad 0 of wave 0 -> f=256

    __shared__ float s_w256[16 + 4 * 16];  // f=256 weights: twr,twi then per-n nwr,nwi
    __shared__ float s_part[2][25];        // per-frame ratio partials, t-parity dbuf

    const int beam = beam_id[b];
    const int pA = n & 1;                  // lane's "A" part: 0=real(even n), 1=imag(odd n)
    const int offA = pA * (NF * NC);
    const int offB = (1 - pA) * (NF * NC);
    const int psel = (n == 1 || n == 2) ? 1 : 0;   // targ part for this lane's partial
    const float nsign = pA ? -1.f : 1.f;

    // weights in registers: 6 float4 per thread
    float4 tw0, tw1, nwA0, nwA1, nwB0, nwB1;
    {
        const float* tp = targ_w + ((size_t)(beam * 2 + psel) * NF + f) * NC;
        tw0 = *(const float4*)(tp);  tw1 = *(const float4*)(tp + 4);
        const float* qp = null_w + ((size_t)((beam * NNUL + n) * 2) * NF + f) * NC;
        nwA0 = *(const float4*)(qp + offA);  nwA1 = *(const float4*)(qp + offA + 4);
        nwB0 = *(const float4*)(qp + offB);  nwB1 = *(const float4*)(qp + offB + 4);
    }
    if (tid < 16) {
        int p = tid >> 3, c = tid & 7;
        s_w256[tid] = targ_w[((size_t)(beam * 2 + p) * NF + 256) * NC + c];
    } else if (tid < 80) {
        int i = tid - 16;
        int nn = i >> 4, p = (i >> 3) & 1, c = i & 7;
        s_w256[tid] = null_w[((size_t)((beam * NNUL + nn) * 2 + p) * NF + 256) * NC + c];
    }
    __syncthreads();

    float phi_r = 0.f, phi_i = 0.f, psd = 0.f;
    float phi_r2 = 0.f, phi_i2 = 0.f, psd2 = 0.f;
    const float a = AL, oma = 1.0f - AL;
    const size_t rowlen = 2 * NF * NC;     // 4112 floats per (b,t)
    const bool in_red = (f >= LOWF) && (f < HIGHF);   // waves 0..4 only

    // one-frame-ahead register prefetch (A = lane's parity part, B = other)
    const float* xrow = x + (size_t)(b * NT + ts) * rowlen + f * NC;
    float4 pA0 = *(const float4*)(xrow + offA);
    float4 pA1 = *(const float4*)(xrow + offA + 4);
    float4 pB0 = *(const float4*)(xrow + offB);
    float4 pB1 = *(const float4*)(xrow + offB + 4);

    float* outT = out + (size_t)NB * NT * NF * NNUL;

    for (int t = ts; t < te; ++t) {
        const float4 A0 = pA0, A1 = pA1, B0 = pB0, B1 = pB1;
        if (t + 1 < te) {
            const float* xr2 = x + (size_t)(b * NT + t + 1) * rowlen + f * NC;
            pA0 = *(const float4*)(xr2 + offA);
            pA1 = *(const float4*)(xr2 + offA + 4);
            pB0 = *(const float4*)(xr2 + offB);
            pB1 = *(const float4*)(xr2 + offB + 4);
        }

        // targ dots via quad butterfly: lane n's partial d covers
        // n0: xr.twr  n1: xi.twi  n2: xr.twi  n3: xi.twr
        const float d = dot8(A0, A1, tw0, tw1);
        const float e = __shfl_xor(d, 1);
        const float u = (n < 2) ? ((n == 0) ? (d - e) : (e - d)) : (d + e);
        const float v = __shfl_xor(u, 2);
        const float tr = (n < 2) ? u : v;
        const float ti = (n < 2) ? v : u;

        // null dots (select-free via A/B address swap; nr needs one sign)
        const float P = dot8(A0, A1, nwA0, nwA1);
        const float Q = dot8(B0, B1, nwB0, nwB1);
        const float nr = nsign * (P - Q);
        const float ni = dot8(A0, A1, nwB0, nwB1) + dot8(B0, B1, nwA0, nwA1);
        const float pw = (dot8(A0, A1, A0, A1) + dot8(B0, B1, B0, B1)) * 0.125f;

        if (t == 0) {  // exact asymmetric init from the reference
            phi_r = oma * tr * nr + ti * ni;
            phi_i = oma * ti * nr - tr * ni;
            psd   = oma * pw;
        } else {
            phi_r = a * phi_r + oma * (tr * nr + ti * ni);
            phi_i = a * phi_i + oma * (ti * nr - tr * ni);
            psd   = a * psd + oma * pw;
        }

        // f=256 on quad 0 of wave 0: weights from LDS, x direct
        float tr2 = 0.f, ti2 = 0.f;
        if (extra) {
            const float* xw = x + (size_t)(b * NT + t) * rowlen + 256 * NC;
            const float4 eA0 = *(const float4*)(xw + offA);
            const float4 eA1 = *(const float4*)(xw + offA + 4);
            const float4 eB0 = *(const float4*)(xw + offB);
            const float4 eB1 = *(const float4*)(xw + offB + 4);
            const float4 etw0 = *(const float4*)&s_w256[psel * 8];
            const float4 etw1 = *(const float4*)&s_w256[psel * 8 + 4];
            const float* nq = &s_w256[16 + n * 16];
            const float4 enA0 = *(const float4*)(nq + pA * 8);
            const float4 enA1 = *(const float4*)(nq + pA * 8 + 4);
            const float4 enB0 = *(const float4*)(nq + (1 - pA) * 8);
            const float4 enB1 = *(const float4*)(nq + (1 - pA) * 8 + 4);
            const float d2 = dot8(eA0, eA1, etw0, etw1);
            const float e2 = __shfl_xor(d2, 1);
            const float u2 = (n < 2) ? ((n == 0) ? (d2 - e2) : (e2 - d2)) : (d2 + e2);
            const float v2 = __shfl_xor(u2, 2);
            tr2 = (n < 2) ? u2 : v2;
            ti2 = (n < 2) ? v2 : u2;
            const float P2 = dot8(eA0, eA1, enA0, enA1);
            const float Q2 = dot8(eB0, eB1, enB0, enB1);
            const float nr2 = nsign * (P2 - Q2);
            const float ni2 = dot8(eA0, eA1, enB0, enB1) + dot8(eB0, eB1, enA0, enA1);
            const float pw2 = (dot8(eA0, eA1, eA0, eA1) + dot8(eB0, eB1, eB0, eB1)) * 0.125f;
            if (t == 0) {
                phi_r2 = oma * tr2 * nr2 + ti2 * ni2;
                phi_i2 = oma * ti2 * nr2 - tr2 * ni2;
                psd2   = oma * pw2;
            } else {
                phi_r2 = a * phi_r2 + oma * (tr2 * nr2 + ti2 * ni2);
                phi_i2 = a * phi_i2 + oma * (ti2 * nr2 - tr2 * ni2);
                psd2   = a * psd2 + oma * pw2;
            }
        }

        if (t >= t0) {
            const float phi = sqrtf(phi_r * phi_r + phi_i * phi_i);
            float dcfv = fminf(fmaxf(phi / (psd + 1e-13f), 0.01f), 1.0f);
            const size_t bt = (size_t)(b * NT + t);
            if (n == 0) outT[(bt * 2 + 0) * NF + f] = tr;
            if (n == 1) outT[(bt * 2 + 1) * NF + f] = ti;
            float dcf2v = 0.f;
            if (extra) {
                const float phi2 = sqrtf(phi_r2 * phi_r2 + phi_i2 * phi_i2);
                dcf2v = fminf(fmaxf(phi2 / (psd2 + 1e-13f), 0.01f), 1.0f);
                if (n == 0) outT[(bt * 2 + 0) * NF + 256] = tr2;
                if (n == 1) outT[(bt * 2 + 1) * NF + 256] = ti2;
            }

            if (t >= 1) {   // block-uniform: ratio path
                // waves 0..4 hold f in [5,70): shfl-reduce over the 16 quads
                if (wid < 5) {
                    float v_phi = in_red ? phi : 0.f;
                    float v_psd = (in_red && n == 0) ? psd : 0.f;
                    #pragma unroll
                    for (int off = 4; off < 64; off <<= 1) {
                        v_phi += __shfl_xor(v_phi, off);
                        v_psd += __shfl_xor(v_psd, off);
                    }
                    float* cell = s_part[t & 1];
                    if (lane < 4)  cell[wid * 5 + lane] = v_phi;   // phi sum for n=lane
                    if (lane == 0) cell[wid * 5 + 4]    = v_psd;   // psd sum
                }
                __syncthreads();
                const float* sp = s_part[t & 1];
                const float pre = sp[4] + sp[9] + sp[14] + sp[19] + sp[24];
                const float aft = sp[n] + sp[5 + n] + sp[10 + n] + sp[15 + n] + sp[20 + n];
                const float ratio = fminf(fmaxf(aft / (pre + 1e-10f), 0.01f), 1.0f);
                dcfv = sqrtf(dcfv * ratio);
                if (extra) dcf2v = sqrtf(dcf2v * ratio);
            }

            out[(bt * NF + f) * NNUL + n] = dcfv;
            if (extra) out[(bt * NF + 256) * NNUL + n] = dcf2v;
        }
    }
}

extern "C" void kernel_launch(void* const* d_in, const int* in_sizes, int n_in,
                              void* d_out, int out_size, void* d_ws, size_t ws_size,
                              hipStream_t stream) {
    const float* x       = (const float*)d_in[0];
    const int*   beam_id = (const int*)d_in[1];
    const float* targ_w  = (const float*)d_in[2];
    const float* null_w  = (const float*)d_in[3];
    float* out           = (float*)d_out;
    (void)d_ws; (void)ws_size;

    dcf_fused_kernel<<<dim3(NB * N_CHUNK), dim3(1024), 0, stream>>>(
        x, beam_id, targ_w, null_w, out);
}

// Round 2
// 133.899 us; speedup vs baseline: 1.0589x; 1.0196x over previous
//
#include <hip/hip_runtime.h>

#define NB 8      // NUM_BLOCK
#define NT 500    // NUM_FRAME
#define NF 257    // NUM_BIN
#define NC 8      // NUM_CH
#define NNUL 4    // NUM_NULL
#define LOWF 5
#define HIGHF 70
#define S_CHUNK 8
#define WARM 4
#define N_CHUNK 63   // ceil(NT / S_CHUNK)
#define AL 0.35f

__device__ __forceinline__ float dot8(const float4& a0, const float4& a1,
                                      const float4& b0, const float4& b1) {
    return a0.x*b0.x + a0.y*b0.y + a0.z*b0.z + a0.w*b0.w
         + a1.x*b1.x + a1.y*b1.y + a1.z*b1.z + a1.w*b1.w;
}

// Fused single-pass kernel, R2: deferred-ratio epilogue.
// Each block covers ALL 257 bins (1024 thr: f = tid>>2, n = tid&3, f=256 on
// tid<4) so the f-in-[5,70) ratio reduction is block-local. R1 applied the
// ratio per frame with a per-frame __syncthreads (9 barriers/block) — that
// coupled all 16 waves to wave 0 (which also owns the f=256 extra path) every
// frame and blocked cross-wave latency hiding (54 us, VALU 44%, HBM 16%).
// R2: during the frame loop, store pre-ratio dcf into s_dcf[frame][tid] and
// the 25 reduction partials into s_part[frame][*] with NO barrier (waves 0..4
// are the only writers of s_part; each thread owns its s_dcf slot). ONE
// __syncthreads after the loop, then a uniform epilogue forms the ratio
// (LDS broadcast reads) and writes final dcf for all frames.
// Barriers/block: 9 -> 2. Waves run the EMA loop fully decoupled.
// Inner per-frame math is the verified R8 body unchanged.
// launch_bounds(1024,4): VGPR cap 128 (cap 64 spills this body).
// LDS ~34 KB -> <=4 blocks/CU; grid 504 blocks gives ~2/CU.
__global__ __launch_bounds__(1024, 4) void dcf_fused_kernel(
    const float* __restrict__ x,           // (NB,NT,2,NF,NC) fp32
    const int* __restrict__ beam_id,       // (NB,)
    const float* __restrict__ targ_w,      // (8,2,NF,NC) fp32
    const float* __restrict__ null_w,      // (8,NNUL,2,NF,NC) fp32
    float* __restrict__ out)               // fp32: dcf (NB,NT,NF,NNUL) then targ (NB,NT,2,NF)
{
    const int tid = threadIdx.x;
    const int bid = blockIdx.x;
    const int b  = bid & 7;
    const int k  = bid >> 3;
    const int t0 = k * S_CHUNK;
    const int te = min(NT, t0 + S_CHUNK);
    int ts = t0 - WARM; if (ts < 0) ts = 0;

    const int f = tid >> 2;                // 0..255
    const int n = tid & 3;
    const int wid = tid >> 6;
    const int lane = tid & 63;
    const bool extra = (tid < 4);          // quad 0 of wave 0 -> f=256

    __shared__ float s_w256[16 + 4 * 16];       // f=256 weights: twr,twi then per-n nwr,nwi
    __shared__ float s_part[S_CHUNK][25];       // per-frame ratio partials (waves 0..4 write)
    __shared__ float s_dcf[S_CHUNK][1028];      // pre-ratio dcf: [frame][tid], +4 for f=256

    const int beam = beam_id[b];
    const int pA = n & 1;                  // lane's "A" part: 0=real(even n), 1=imag(odd n)
    const int offA = pA * (NF * NC);
    const int offB = (1 - pA) * (NF * NC);
    const int psel = (n == 1 || n == 2) ? 1 : 0;   // targ part for this lane's partial
    const float nsign = pA ? -1.f : 1.f;

    // weights in registers: 6 float4 per thread
    float4 tw0, tw1, nwA0, nwA1, nwB0, nwB1;
    {
        const float* tp = targ_w + ((size_t)(beam * 2 + psel) * NF + f) * NC;
        tw0 = *(const float4*)(tp);  tw1 = *(const float4*)(tp + 4);
        const float* qp = null_w + ((size_t)((beam * NNUL + n) * 2) * NF + f) * NC;
        nwA0 = *(const float4*)(qp + offA);  nwA1 = *(const float4*)(qp + offA + 4);
        nwB0 = *(const float4*)(qp + offB);  nwB1 = *(const float4*)(qp + offB + 4);
    }
    if (tid < 16) {
        int p = tid >> 3, c = tid & 7;
        s_w256[tid] = targ_w[((size_t)(beam * 2 + p) * NF + 256) * NC + c];
    } else if (tid < 80) {
        int i = tid - 16;
        int nn = i >> 4, p = (i >> 3) & 1, c = i & 7;
        s_w256[tid] = null_w[((size_t)((beam * NNUL + nn) * 2 + p) * NF + 256) * NC + c];
    }
    __syncthreads();   // barrier 1 of 2 (weights visible)

    float phi_r = 0.f, phi_i = 0.f, psd = 0.f;
    float phi_r2 = 0.f, phi_i2 = 0.f, psd2 = 0.f;
    const float a = AL, oma = 1.0f - AL;
    const size_t rowlen = 2 * NF * NC;     // 4112 floats per (b,t)
    const bool in_red = (f >= LOWF) && (f < HIGHF);   // waves 0..4 only

    // one-frame-ahead register prefetch (A = lane's parity part, B = other)
    const float* xrow = x + (size_t)(b * NT + ts) * rowlen + f * NC;
    float4 pA0 = *(const float4*)(xrow + offA);
    float4 pA1 = *(const float4*)(xrow + offA + 4);
    float4 pB0 = *(const float4*)(xrow + offB);
    float4 pB1 = *(const float4*)(xrow + offB + 4);

    float* outT = out + (size_t)NB * NT * NF * NNUL;

    for (int t = ts; t < te; ++t) {
        const float4 A0 = pA0, A1 = pA1, B0 = pB0, B1 = pB1;
        if (t + 1 < te) {
            const float* xr2 = x + (size_t)(b * NT + t + 1) * rowlen + f * NC;
            pA0 = *(const float4*)(xr2 + offA);
            pA1 = *(const float4*)(xr2 + offA + 4);
            pB0 = *(const float4*)(xr2 + offB);
            pB1 = *(const float4*)(xr2 + offB + 4);
        }

        // targ dots via quad butterfly: lane n's partial d covers
        // n0: xr.twr  n1: xi.twi  n2: xr.twi  n3: xi.twr
        const float d = dot8(A0, A1, tw0, tw1);
        const float e = __shfl_xor(d, 1);
        const float u = (n < 2) ? ((n == 0) ? (d - e) : (e - d)) : (d + e);
        const float v = __shfl_xor(u, 2);
        const float tr = (n < 2) ? u : v;
        const float ti = (n < 2) ? v : u;

        // null dots (select-free via A/B address swap; nr needs one sign)
        const float P = dot8(A0, A1, nwA0, nwA1);
        const float Q = dot8(B0, B1, nwB0, nwB1);
        const float nr = nsign * (P - Q);
        const float ni = dot8(A0, A1, nwB0, nwB1) + dot8(B0, B1, nwA0, nwA1);
        const float pw = (dot8(A0, A1, A0, A1) + dot8(B0, B1, B0, B1)) * 0.125f;

        if (t == 0) {  // exact asymmetric init from the reference
            phi_r = oma * tr * nr + ti * ni;
            phi_i = oma * ti * nr - tr * ni;
            psd   = oma * pw;
        } else {
            phi_r = a * phi_r + oma * (tr * nr + ti * ni);
            phi_i = a * phi_i + oma * (ti * nr - tr * ni);
            psd   = a * psd + oma * pw;
        }

        // f=256 on quad 0 of wave 0: weights from LDS, x direct
        float tr2 = 0.f, ti2 = 0.f;
        if (extra) {
            const float* xw = x + (size_t)(b * NT + t) * rowlen + 256 * NC;
            const float4 eA0 = *(const float4*)(xw + offA);
            const float4 eA1 = *(const float4*)(xw + offA + 4);
            const float4 eB0 = *(const float4*)(xw + offB);
            const float4 eB1 = *(const float4*)(xw + offB + 4);
            const float4 etw0 = *(const float4*)&s_w256[psel * 8];
            const float4 etw1 = *(const float4*)&s_w256[psel * 8 + 4];
            const float* nq = &s_w256[16 + n * 16];
            const float4 enA0 = *(const float4*)(nq + pA * 8);
            const float4 enA1 = *(const float4*)(nq + pA * 8 + 4);
            const float4 enB0 = *(const float4*)(nq + (1 - pA) * 8);
            const float4 enB1 = *(const float4*)(nq + (1 - pA) * 8 + 4);
            const float d2 = dot8(eA0, eA1, etw0, etw1);
            const float e2 = __shfl_xor(d2, 1);
            const float u2 = (n < 2) ? ((n == 0) ? (d2 - e2) : (e2 - d2)) : (d2 + e2);
            const float v2 = __shfl_xor(u2, 2);
            tr2 = (n < 2) ? u2 : v2;
            ti2 = (n < 2) ? v2 : u2;
            const float P2 = dot8(eA0, eA1, enA0, enA1);
            const float Q2 = dot8(eB0, eB1, enB0, enB1);
            const float nr2 = nsign * (P2 - Q2);
            const float ni2 = dot8(eA0, eA1, enB0, enB1) + dot8(eB0, eB1, enA0, enA1);
            const float pw2 = (dot8(eA0, eA1, eA0, eA1) + dot8(eB0, eB1, eB0, eB1)) * 0.125f;
            if (t == 0) {
                phi_r2 = oma * tr2 * nr2 + ti2 * ni2;
                phi_i2 = oma * ti2 * nr2 - tr2 * ni2;
                psd2   = oma * pw2;
            } else {
                phi_r2 = a * phi_r2 + oma * (tr2 * nr2 + ti2 * ni2);
                phi_i2 = a * phi_i2 + oma * (ti2 * nr2 - tr2 * ni2);
                psd2   = a * psd2 + oma * pw2;
            }
        }

        if (t >= t0) {
            const int fr = t - t0;
            const float phi = sqrtf(phi_r * phi_r + phi_i * phi_i);
            const float dcfv = fminf(fmaxf(phi / (psd + 1e-13f), 0.01f), 1.0f);
            const size_t bt = (size_t)(b * NT + t);
            if (n == 0) outT[(bt * 2 + 0) * NF + f] = tr;
            if (n == 1) outT[(bt * 2 + 1) * NF + f] = ti;
            s_dcf[fr][tid] = dcfv;                       // pre-ratio, own slot
            if (extra) {
                const float phi2 = sqrtf(phi_r2 * phi_r2 + phi_i2 * phi_i2);
                const float dcf2v = fminf(fmaxf(phi2 / (psd2 + 1e-13f), 0.01f), 1.0f);
                s_dcf[fr][1024 + n] = dcf2v;
                if (n == 0) outT[(bt * 2 + 0) * NF + 256] = tr2;
                if (n == 1) outT[(bt * 2 + 1) * NF + 256] = ti2;
            }
            // ratio partials: waves 0..4 hold f in [5,70); NO barrier here
            if (wid < 5) {
                float v_phi = in_red ? phi : 0.f;
                float v_psd = (in_red && n == 0) ? psd : 0.f;
                #pragma unroll
                for (int off = 4; off < 64; off <<= 1) {
                    v_phi += __shfl_xor(v_phi, off);
                    v_psd += __shfl_xor(v_psd, off);
                }
                if (lane < 4)  s_part[fr][wid * 5 + lane] = v_phi;   // phi sum, n=lane
                if (lane == 0) s_part[fr][wid * 5 + 4]    = v_psd;   // psd sum
            }
        }
    }

    __syncthreads();   // barrier 2 of 2: all frames' s_dcf + s_part visible

    // uniform epilogue: apply ratio, write final dcf for all output frames
    const int nf = te - t0;
    for (int fr = 0; fr < nf; ++fr) {
        const int t = t0 + fr;
        const size_t bt = (size_t)(b * NT + t);
        float dcfv = s_dcf[fr][tid];
        float dcf2v = extra ? s_dcf[fr][1024 + n] : 0.f;
        if (t >= 1) {
            const float* sp = s_part[fr];
            const float pre = sp[4] + sp[9] + sp[14] + sp[19] + sp[24];
            const float aft = sp[n] + sp[5 + n] + sp[10 + n] + sp[15 + n] + sp[20 + n];
            const float ratio = fminf(fmaxf(aft / (pre + 1e-10f), 0.01f), 1.0f);
            dcfv = sqrtf(dcfv * ratio);
            if (extra) dcf2v = sqrtf(dcf2v * ratio);
        }
        out[(bt * NF + f) * NNUL + n] = dcfv;
        if (extra) out[(bt * NF + 256) * NNUL + n] = dcf2v;
    }
}

extern "C" void kernel_launch(void* const* d_in, const int* in_sizes, int n_in,
                              void* d_out, int out_size, void* d_ws, size_t ws_size,
                              hipStream_t stream) {
    const float* x       = (const float*)d_in[0];
    const int*   beam_id = (const int*)d_in[1];
    const float* targ_w  = (const float*)d_in[2];
    const float* null_w  = (const float*)d_in[3];
    float* out           = (float*)d_out;
    (void)d_ws; (void)ws_size;

    dcf_fused_kernel<<<dim3(NB * N_CHUNK), dim3(1024), 0, stream>>>(
        x, beam_id, targ_w, null_w, out);
}